// Round 6
// baseline (753.098 us; speedup 1.0000x reference)
//
#include <hip/hip_runtime.h>

#define NT 128      // num tags
#define SEQ 1024    // sequence length
#define NB 256      // batch

typedef _Float16 half2v __attribute__((ext_vector_type(2)));

// One DPP max step on the VALU pipe (no DS/lgkmcnt involvement).
#define DPP_MAX_STEP(x, ctrl)                                                   \
    fmaxf((x), __builtin_bit_cast(float, __builtin_amdgcn_update_dpp(           \
        __builtin_bit_cast(int, (x)), __builtin_bit_cast(int, (x)),             \
        (ctrl), 0xf, 0xf, false)))

__device__ __forceinline__ float wave_max_dpp(float x) {
    x = DPP_MAX_STEP(x, 0x111);   // row_shr:1
    x = DPP_MAX_STEP(x, 0x112);   // row_shr:2
    x = DPP_MAX_STEP(x, 0x114);   // row_shr:4
    x = DPP_MAX_STEP(x, 0x118);   // row_shr:8
    x = DPP_MAX_STEP(x, 0x142);   // row_bcast:15
    x = DPP_MAX_STEP(x, 0x143);   // row_bcast:31
    return __builtin_bit_cast(float, __builtin_amdgcn_readlane(
        __builtin_bit_cast(int, x), 63));
}

// ONE WAVE per batch element. 256 blocks x 64 threads. Lane l owns output
// columns c0=2l, c1=2l+1; E (prob domain) in registers as f16 pairs (128
// VGPRs). The p vector is NEVER round-tripped through LDS in the scan:
// lane r's packed f16 pair (p[2r],p[2r+1]) is broadcast wave-uniformly with
// v_readlane_b32 and consumed as the scalar operand of v_dot2_f32_f16.
// Per step: 64 readlane + 128 fdot2, all on the VALU pipe — no DS latency,
// no lgkmcnt, no barrier. Renorm scale folded into next step's emission
// factor; DPP-max/rcp/log/exp overlap the next matvec's issue stream.
__global__ __launch_bounds__(64, 1) void crf_scan_kernel(
    const float* __restrict__ emissions,    // [B,S,T]
    const float* __restrict__ masks,        // [B,S]
    const int*   __restrict__ tags,         // [B,S]
    const float* __restrict__ transitions,  // [T,T] (log domain)
    const float* __restrict__ start_t,      // [T]
    const float* __restrict__ end_t,        // [T]
    float* __restrict__ out_per_batch)      // [B]
{
    const int b  = blockIdx.x;
    const int l  = threadIdx.x;          // 0..63
    const int c0 = 2 * l;
    const int c1 = 2 * l + 1;

    __shared__ float msk_s[SEQ];

    // ---- E columns into registers, f16 pairs along the row (i) dim ----
    // E0[r] = (exp(T[2r][c0]), exp(T[2r+1][c0])), E1 same for c1.
    half2v E0[64], E1[64];
    #pragma unroll
    for (int r = 0; r < 64; ++r) {
        float2 ta = *(const float2*)&transitions[(2 * r)     * NT + c0];
        float2 tb = *(const float2*)&transitions[(2 * r + 1) * NT + c0];
        E0[r] = half2v{(_Float16)__expf(ta.x), (_Float16)__expf(tb.x)};
        E1[r] = half2v{(_Float16)__expf(ta.y), (_Float16)__expf(tb.y)};
    }

    // masks into LDS (same wave writes then reads -> in-order DS, no barrier)
    for (int s = l; s < SEQ; s += 64)
        msk_s[s] = masks[b * SEQ + s];

    // ---- init: P = exp(start), offset = 0 ----
    float cur0 = __expf(start_t[c0]);
    float cur1 = __expf(start_t[c1]);
    int   pk   = __builtin_bit_cast(int, __builtin_amdgcn_cvt_pkrtz(cur0, cur1));
    float offset = 0.0f;

    // first step's scale, folded into ex
    float mx  = wave_max_dpp(fmaxf(cur0, cur1));
    float inv = __builtin_amdgcn_rcpf(256.0f * mx);
    float offadd = __logf(mx) + 5.545177444479562f;   // log(256*mx)

    const float* eb = emissions + (size_t)b * SEQ * NT;

    float2 em0 = *(const float2*)&eb[(size_t)0 * NT + c0];
    float2 em1 = *(const float2*)&eb[(size_t)1 * NT + c0];
    float2 ex;
    ex.x = __expf(em0.x) * inv;
    ex.y = __expf(em0.y) * inv;

    float mcur = msk_s[0];               // mask for step s (preloaded)

    for (int s = 0; s < SEQ; ++s) {
        // prefetch emission 2 steps ahead (covers HBM latency)
        int spre = (s + 2 < SEQ) ? s + 2 : SEQ - 1;
        float2 em2 = *(const float2*)&eb[(size_t)spre * NT + c0];

        // matvec: v_j = (sum_r (p[2r],p[2r+1]) . E[2r:2r+2][j]) * ex_j
        // p pair broadcast from lane r via readlane (SGPR operand of fdot2).
        float A0 = 0.f, A1 = 0.f, A2 = 0.f, A3 = 0.f;
        float B0 = 0.f, B1 = 0.f, B2 = 0.f, B3 = 0.f;
        #pragma unroll
        for (int r = 0; r < 64; r += 4) {
            half2v p0 = __builtin_bit_cast(half2v, __builtin_amdgcn_readlane(pk, r + 0));
            half2v p1 = __builtin_bit_cast(half2v, __builtin_amdgcn_readlane(pk, r + 1));
            half2v p2 = __builtin_bit_cast(half2v, __builtin_amdgcn_readlane(pk, r + 2));
            half2v p3 = __builtin_bit_cast(half2v, __builtin_amdgcn_readlane(pk, r + 3));
            A0 = __builtin_amdgcn_fdot2(p0, E0[r + 0], A0, false);
            B0 = __builtin_amdgcn_fdot2(p0, E1[r + 0], B0, false);
            A1 = __builtin_amdgcn_fdot2(p1, E0[r + 1], A1, false);
            B1 = __builtin_amdgcn_fdot2(p1, E1[r + 1], B1, false);
            A2 = __builtin_amdgcn_fdot2(p2, E0[r + 2], A2, false);
            B2 = __builtin_amdgcn_fdot2(p2, E1[r + 2], B2, false);
            A3 = __builtin_amdgcn_fdot2(p3, E0[r + 3], A3, false);
            B3 = __builtin_amdgcn_fdot2(p3, E1[r + 3], B3, false);
        }
        float v0 = ((A0 + A1) + (A2 + A3)) * ex.x;
        float v1 = ((B0 + B1) + (B2 + B3)) * ex.y;

        // accept/reject (wave-uniform), account the scale folded into ex
        bool upd = mcur > 0.0f;
        if (upd) { cur0 = v0; cur1 = v1; offset += offadd; }

        // repack ASAP: next step's readlane stream depends only on this
        pk = __builtin_bit_cast(int, __builtin_amdgcn_cvt_pkrtz(cur0, cur1));

        mcur = msk_s[(s + 1 < SEQ) ? s + 1 : SEQ - 1];

        // next-step scale — VALU DPP max; consumed 384+ cyc later via ex
        mx  = wave_max_dpp(fmaxf(cur0, cur1));
        inv = __builtin_amdgcn_rcpf(256.0f * mx);
        offadd = __logf(mx) + 5.545177444479562f;

        ex.x = __expf(em1.x) * inv;
        ex.y = __expf(em1.y) * inv;
        em1 = em2;
    }

    // ---- log_z = offset + log( sum_j P_j * exp(end_j) ) ----
    float term = cur0 * __expf(end_t[c0]) + cur1 * __expf(end_t[c1]);
    #pragma unroll
    for (int off = 32; off; off >>= 1)
        term += __shfl_xor(term, off);
    float log_z = offset + __logf(term);

    // ---- gold-path score (single wave, 16 s-iters/lane) ----
    const int tb = b * SEQ;
    float sc = 0.0f, sm = 0.0f;
    for (int s = l; s < SEQ; s += 64) {
        float m = msk_s[s];
        sm += m;
        if (s < SEQ - 1) {
            int tg  = tags[tb + s];
            int tg1 = tags[tb + s + 1];
            sc += eb[(size_t)s * NT + tg] * m;
            sc += transitions[tg * NT + tg1] * msk_s[s + 1];
        }
    }
    #pragma unroll
    for (int off = 32; off; off >>= 1) {
        sc += __shfl_xor(sc, off);
        sm += __shfl_xor(sm, off);
    }

    if (l == 0) {
        int tg0 = tags[tb];
        int tgl = tags[tb + SEQ - 1];
        sc += start_t[tg0];
        int last_ix = (int)fmaxf(sm - 1.0f, 0.0f);
        float ml = msk_s[SEQ - 1];
        sc += eb[(size_t)last_ix * NT + tgl] * ml;
        sc += end_t[tgl] * ml;
        out_per_batch[b] = log_z - sc;
    }
}

// mean over batch -> scalar output
__global__ void crf_reduce_kernel(const float* __restrict__ pb, float* __restrict__ out)
{
    float v = pb[threadIdx.x];   // 256 threads, one per batch
    #pragma unroll
    for (int off = 32; off; off >>= 1)
        v += __shfl_xor(v, off);
    __shared__ float s4[4];
    if ((threadIdx.x & 63) == 0) s4[threadIdx.x >> 6] = v;
    __syncthreads();
    if (threadIdx.x == 0)
        out[0] = (s4[0] + s4[1] + s4[2] + s4[3]) * (1.0f / 256.0f);
}

extern "C" void kernel_launch(void* const* d_in, const int* in_sizes, int n_in,
                              void* d_out, int out_size, void* d_ws, size_t ws_size,
                              hipStream_t stream) {
    const float* emissions   = (const float*)d_in[0];
    const float* masks       = (const float*)d_in[1];
    const int*   tags        = (const int*)  d_in[2];
    const float* transitions = (const float*)d_in[3];
    const float* start_t     = (const float*)d_in[4];
    const float* end_t       = (const float*)d_in[5];
    float* per_batch = (float*)d_ws;

    crf_scan_kernel<<<NB, 64, 0, stream>>>(emissions, masks, tags, transitions,
                                           start_t, end_t, per_batch);
    crf_reduce_kernel<<<1, 256, 0, stream>>>(per_batch, (float*)d_out);
}

// Round 7
// 653.411 us; speedup vs baseline: 1.1526x; 1.1526x over previous
//
#include <hip/hip_runtime.h>

#define NT 128      // num tags
#define SEQ 1024    // sequence length
#define NB 256      // batch

typedef _Float16 half2v __attribute__((ext_vector_type(2)));

// One DPP max step on the VALU pipe (no DS/lgkmcnt involvement).
#define DPP_MAX_STEP(x, ctrl)                                                   \
    fmaxf((x), __builtin_bit_cast(float, __builtin_amdgcn_update_dpp(           \
        __builtin_bit_cast(int, (x)), __builtin_bit_cast(int, (x)),             \
        (ctrl), 0xf, 0xf, false)))

__device__ __forceinline__ float wave_max_dpp(float x) {
    x = DPP_MAX_STEP(x, 0x111);   // row_shr:1
    x = DPP_MAX_STEP(x, 0x112);   // row_shr:2
    x = DPP_MAX_STEP(x, 0x114);   // row_shr:4
    x = DPP_MAX_STEP(x, 0x118);   // row_shr:8
    x = DPP_MAX_STEP(x, 0x142);   // row_bcast:15
    x = DPP_MAX_STEP(x, 0x143);   // row_bcast:31
    return __builtin_bit_cast(float, __builtin_amdgcn_readlane(
        __builtin_bit_cast(int, x), 63));
}

// One scan step. RC = ring slot for THIS step (prefetch target, em[s+4]),
// RN = ring slot holding em[s+1], MC = mask ring slot for this step.
// The em/mask loads go DIRECTLY into static ring registers so the vmcnt
// wait lands ~3.5 steps (>1500 cyc) after issue — covers HBM latency.
#define CRF_STEP(RC, RN, MC, DO_PRE, K)                                          \
    {                                                                            \
        float mcur = MC;                                                         \
        if (DO_PRE) {                                                            \
            RC = *(const float2*)(emp + (K) * NT);                               \
            MC = mpp[K];                                                         \
        }                                                                        \
        float A0=0.f,A1=0.f,A2=0.f,A3=0.f,B0=0.f,B1=0.f,B2=0.f,B3=0.f;           \
        _Pragma("unroll")                                                        \
        for (int c = 0; c < 16; ++c) {                                           \
            uint4 q = p4r[c];                                                    \
            half2v p0 = __builtin_bit_cast(half2v, q.x);                         \
            half2v p1 = __builtin_bit_cast(half2v, q.y);                         \
            half2v p2 = __builtin_bit_cast(half2v, q.z);                         \
            half2v p3 = __builtin_bit_cast(half2v, q.w);                         \
            A0 = __builtin_amdgcn_fdot2(p0, E0[4*c+0], A0, false);               \
            B0 = __builtin_amdgcn_fdot2(p0, E1[4*c+0], B0, false);               \
            A1 = __builtin_amdgcn_fdot2(p1, E0[4*c+1], A1, false);               \
            B1 = __builtin_amdgcn_fdot2(p1, E1[4*c+1], B1, false);               \
            A2 = __builtin_amdgcn_fdot2(p2, E0[4*c+2], A2, false);               \
            B2 = __builtin_amdgcn_fdot2(p2, E1[4*c+2], B2, false);               \
            A3 = __builtin_amdgcn_fdot2(p3, E0[4*c+3], A3, false);               \
            B3 = __builtin_amdgcn_fdot2(p3, E1[4*c+3], B3, false);               \
        }                                                                        \
        float v0 = ((A0 + A1) + (A2 + A3)) * ex.x;                               \
        float v1 = ((B0 + B1) + (B2 + B3)) * ex.y;                               \
        if (mcur > 0.0f) { cur0 = v0; cur1 = v1; offset += offadd; }             \
        p_h[l] = __builtin_bit_cast(unsigned int,                                \
                                    __builtin_amdgcn_cvt_pkrtz(cur0, cur1));     \
        mx  = wave_max_dpp(fmaxf(cur0, cur1));                                   \
        inv = __builtin_amdgcn_rcpf(256.0f * mx);                                \
        offadd = __logf(mx) + 5.545177444479562f;                                \
        ex.x = __expf(RN.x) * inv;                                               \
        ex.y = __expf(RN.y) * inv;                                               \
    }

// ONE WAVE per batch element. 256 blocks x 64 threads. Lane l owns output
// columns c0=2l, c1=2l+1; E (prob domain) in registers as f16 pairs (128
// VGPRs). Matvec: p broadcast from LDS as uint4 (conflict-free same-address
// reads, DS pipe) into v_dot2_f32_f16 (fp32 accumulate). Renorm scale folded
// into next step's emission factor; DPP-max/rcp/log/exp overlap the LDS
// store->read turnaround. No __syncthreads in the scan (single wave,
// in-order DS pipe).
__global__ __launch_bounds__(64, 1) void crf_scan_kernel(
    const float* __restrict__ emissions,    // [B,S,T]
    const float* __restrict__ masks,        // [B,S]
    const int*   __restrict__ tags,         // [B,S]
    const float* __restrict__ transitions,  // [T,T] (log domain)
    const float* __restrict__ start_t,      // [T]
    const float* __restrict__ end_t,        // [T]
    float* __restrict__ out_per_batch)      // [B]
{
    const int b  = blockIdx.x;
    const int l  = threadIdx.x;          // 0..63
    const int c0 = 2 * l;
    const int c1 = 2 * l + 1;

    __shared__ unsigned int p_h[64];     // packed f16 pairs: (p[2r], p[2r+1])
    __shared__ float msk_s[SEQ];         // for the epilogue score pass

    // ---- E columns into registers, f16 pairs along the row (i) dim ----
    half2v E0[64], E1[64];
    #pragma unroll
    for (int r = 0; r < 64; ++r) {
        float2 ta = *(const float2*)&transitions[(2 * r)     * NT + c0];
        float2 tb = *(const float2*)&transitions[(2 * r + 1) * NT + c0];
        E0[r] = half2v{(_Float16)__expf(ta.x), (_Float16)__expf(tb.x)};
        E1[r] = half2v{(_Float16)__expf(ta.y), (_Float16)__expf(tb.y)};
    }

    for (int s = l; s < SEQ; s += 64)
        msk_s[s] = masks[b * SEQ + s];

    // ---- init: P = exp(start), offset = 0 ----
    float cur0 = __expf(start_t[c0]);
    float cur1 = __expf(start_t[c1]);
    p_h[l] = __builtin_bit_cast(unsigned int, __builtin_amdgcn_cvt_pkrtz(cur0, cur1));
    float offset = 0.0f;

    float mx  = wave_max_dpp(fmaxf(cur0, cur1));
    float inv = __builtin_amdgcn_rcpf(256.0f * mx);
    float offadd = __logf(mx) + 5.545177444479562f;   // log(256*mx)

    const float* eb  = emissions + (size_t)b * SEQ * NT;
    const float* mkp = masks + b * SEQ;

    // depth-4 rings: slot k holds em/mask for step s with s&3==k
    float2 ring0 = *(const float2*)&eb[(size_t)0 * NT + c0];
    float2 ring1 = *(const float2*)&eb[(size_t)1 * NT + c0];
    float2 ring2 = *(const float2*)&eb[(size_t)2 * NT + c0];
    float2 ring3 = *(const float2*)&eb[(size_t)3 * NT + c0];
    float  mr0 = mkp[0], mr1 = mkp[1], mr2 = mkp[2], mr3 = mkp[3];

    float2 ex;
    ex.x = __expf(ring0.x) * inv;
    ex.y = __expf(ring0.y) * inv;

    const float* emp = eb + 4 * NT + c0;   // points at em[s+4] pair for s=0
    const float* mpp = mkp + 4;

    const uint4* p4r = (const uint4*)p_h;

    // main loop: steps 0..1019, unrolled x4 so ring slots are static regs
    for (int it = 0; it < (SEQ - 4) / 4; ++it) {
        CRF_STEP(ring0, ring1, mr0, true, 0)
        CRF_STEP(ring1, ring2, mr1, true, 1)
        CRF_STEP(ring2, ring3, mr2, true, 2)
        CRF_STEP(ring3, ring0, mr3, true, 3)
        emp += 4 * NT;
        mpp += 4;
    }
    // tail: steps 1020..1023 (no prefetch; final ex compute is dead)
    CRF_STEP(ring0, ring1, mr0, false, 0)
    CRF_STEP(ring1, ring2, mr1, false, 0)
    CRF_STEP(ring2, ring3, mr2, false, 0)
    CRF_STEP(ring3, ring3, mr3, false, 0)

    // ---- log_z = offset + log( sum_j P_j * exp(end_j) ) ----
    float term = cur0 * __expf(end_t[c0]) + cur1 * __expf(end_t[c1]);
    #pragma unroll
    for (int off = 32; off; off >>= 1)
        term += __shfl_xor(term, off);
    float log_z = offset + __logf(term);

    // ---- gold-path score (single wave, 16 s-iters/lane) ----
    const int tb = b * SEQ;
    float sc = 0.0f, sm = 0.0f;
    for (int s = l; s < SEQ; s += 64) {
        float m = msk_s[s];
        sm += m;
        if (s < SEQ - 1) {
            int tg  = tags[tb + s];
            int tg1 = tags[tb + s + 1];
            sc += eb[(size_t)s * NT + tg] * m;
            sc += transitions[tg * NT + tg1] * msk_s[s + 1];
        }
    }
    #pragma unroll
    for (int off = 32; off; off >>= 1) {
        sc += __shfl_xor(sc, off);
        sm += __shfl_xor(sm, off);
    }

    if (l == 0) {
        int tg0 = tags[tb];
        int tgl = tags[tb + SEQ - 1];
        sc += start_t[tg0];
        int last_ix = (int)fmaxf(sm - 1.0f, 0.0f);
        float ml = msk_s[SEQ - 1];
        sc += eb[(size_t)last_ix * NT + tgl] * ml;
        sc += end_t[tgl] * ml;
        out_per_batch[b] = log_z - sc;
    }
}

// mean over batch -> scalar output
__global__ void crf_reduce_kernel(const float* __restrict__ pb, float* __restrict__ out)
{
    float v = pb[threadIdx.x];   // 256 threads, one per batch
    #pragma unroll
    for (int off = 32; off; off >>= 1)
        v += __shfl_xor(v, off);
    __shared__ float s4[4];
    if ((threadIdx.x & 63) == 0) s4[threadIdx.x >> 6] = v;
    __syncthreads();
    if (threadIdx.x == 0)
        out[0] = (s4[0] + s4[1] + s4[2] + s4[3]) * (1.0f / 256.0f);
}

extern "C" void kernel_launch(void* const* d_in, const int* in_sizes, int n_in,
                              void* d_out, int out_size, void* d_ws, size_t ws_size,
                              hipStream_t stream) {
    const float* emissions   = (const float*)d_in[0];
    const float* masks       = (const float*)d_in[1];
    const int*   tags        = (const int*)  d_in[2];
    const float* transitions = (const float*)d_in[3];
    const float* start_t     = (const float*)d_in[4];
    const float* end_t       = (const float*)d_in[5];
    float* per_batch = (float*)d_ws;

    crf_scan_kernel<<<NB, 64, 0, stream>>>(emissions, masks, tags, transitions,
                                           start_t, end_t, per_batch);
    crf_reduce_kernel<<<1, 256, 0, stream>>>(per_batch, (float*)d_out);
}